// Round 5
// baseline (5178.034 us; speedup 1.0000x reference)
//
#include <hip/hip_runtime.h>
#include <hip/hip_bf16.h>
#include <math.h>

#define B_   128
#define L_   16
#define E_   768
#define D_   384
#define H_   12
#define HD_  64
#define NL_  6
#define SEQ_ 12
#define LN_EPS 0.001f
#define WLS   7077888               // bf16 elems per layer weight pack
#define BQS   2304

typedef __attribute__((ext_vector_type(8))) short bf16x8;
typedef __attribute__((ext_vector_type(4))) float f32x4;
typedef unsigned long long u64;

#define GLOAD_LDS16(g, l) \
    __builtin_amdgcn_global_load_lds((__attribute__((address_space(1))) const void*)(g), \
                                     (__attribute__((address_space(3))) void*)(l), 16, 0, 0)

// ---------------- build x0 for CL lidx starting at cb (cos inlined) ----------------
__global__ __launch_bounds__(256) void k_x0(const float* __restrict__ X,
                                            const float* __restrict__ targets,
                                            const int* __restrict__ perms,
                                            const float* __restrict__ om,
                                            const float* __restrict__ ph,
                                            float* __restrict__ x, int cb, int ntok) {
    int i = blockIdx.x * 256 + threadIdx.x;
    if (i >= ntok*E_) return;
    int e   = i % E_;
    int tok = i / E_;
    int s   = tok % SEQ_;
    int bi  = (tok / SEQ_) % B_;
    int c   = tok / (SEQ_*B_);
    int cl  = cb + c;
    int lidx = cl + 1;
    int pb  = perms[cl*B_ + bi];
    float val;
    if (s < 3) {
        int t  = (e < D_) ? (L_ - lidx) : (L_ - lidx - 1);
        int dd = (e < D_) ? e : (e - D_);
        float xv = X[(pb*L_ + t)*3 + s];
        val = cosf(xv * om[s*D_ + dd] + ph[s*D_ + dd]);
    } else if (s < 6) {
        int t = (17 - lidx) & 15;
        val = targets[(pb*L_ + t)*3 + (s - 3)];
    } else {
        val = (float)(L_ - lidx);
    }
    x[i] = val;
}

// ---------------- LayerNorm: one wave per token, no barriers ----------------
__global__ __launch_bounds__(256) void k_ln(const float* __restrict__ x,
                                            const float* __restrict__ g,
                                            const float* __restrict__ b,
                                            __hip_bfloat16* __restrict__ h) {
    int gi = blockIdx.x * 256 + threadIdx.x;
    int tok = gi >> 6, lane = gi & 63;
    const float4* xr = (const float4*)(x + (size_t)tok * E_);
    float4 v0 = xr[lane], v1 = xr[lane + 64], v2 = xr[lane + 128];
    float s = v0.x+v0.y+v0.z+v0.w + v1.x+v1.y+v1.z+v1.w + v2.x+v2.y+v2.z+v2.w;
    #pragma unroll
    for (int o = 32; o > 0; o >>= 1) s += __shfl_xor(s, o, 64);
    float mu = s * (1.0f / E_);
    v0.x-=mu; v0.y-=mu; v0.z-=mu; v0.w-=mu;
    v1.x-=mu; v1.y-=mu; v1.z-=mu; v1.w-=mu;
    v2.x-=mu; v2.y-=mu; v2.z-=mu; v2.w-=mu;
    float q = v0.x*v0.x+v0.y*v0.y+v0.z*v0.z+v0.w*v0.w
            + v1.x*v1.x+v1.y*v1.y+v1.z*v1.z+v1.w*v1.w
            + v2.x*v2.x+v2.y*v2.y+v2.z*v2.z+v2.w*v2.w;
    #pragma unroll
    for (int o = 32; o > 0; o >>= 1) q += __shfl_xor(q, o, 64);
    float rstd = rsqrtf(q * (1.0f / E_) + LN_EPS);
    const float4* g4 = (const float4*)g;
    const float4* b4 = (const float4*)b;
    ushort4* h4 = (ushort4*)(h + (size_t)tok * E_);
    #pragma unroll
    for (int k = 0; k < 3; k++) {
        float4 v = (k == 0) ? v0 : (k == 1) ? v1 : v2;
        float4 gg = g4[lane + k*64], bb = b4[lane + k*64];
        ushort4 o;
        o.x = __bfloat16_as_ushort(__float2bfloat16(v.x * rstd * gg.x + bb.x));
        o.y = __bfloat16_as_ushort(__float2bfloat16(v.y * rstd * gg.y + bb.y));
        o.z = __bfloat16_as_ushort(__float2bfloat16(v.z * rstd * gg.z + bb.z));
        o.w = __bfloat16_as_ushort(__float2bfloat16(v.w * rstd * gg.w + bb.w));
        h4[lane + k*64] = o;
    }
}

// ---------------- weight transpose+convert fp32[K][N] -> bf16[N][K], nl layers ----------------
__global__ __launch_bounds__(256) void k_cvt(const float* __restrict__ Wq,
                                             const float* __restrict__ Wk,
                                             const float* __restrict__ Wv,
                                             const float* __restrict__ Wo,
                                             const float* __restrict__ W1,
                                             const float* __restrict__ W2,
                                             const float* __restrict__ bq,
                                             const float* __restrict__ bk,
                                             const float* __restrict__ bv,
                                             __hip_bfloat16* __restrict__ wl0,
                                             float* __restrict__ bqkv0, int lbase) {
    int bid = blockIdx.x;
    int l   = lbase + bid / 6913;
    bid %= 6913;
    __hip_bfloat16* wl = wl0 + (size_t)(l - lbase) * WLS;
    float* bqkv = bqkv0 + (l - lbase) * BQS;
    int tid = threadIdx.x;
    if (bid == 6912) {
        for (int i = tid; i < 2304; i += 256) {
            float v = (i < 768) ? bq[l*768 + i] : (i < 1536) ? bk[l*768 + i - 768]
                                                             : bv[l*768 + i - 1536];
            bqkv[i] = v;
        }
        return;
    }
    const float* src; __hip_bfloat16* dst; int K, N, ti, tj;
    if (bid < 1728) {
        int part = bid / 576, idx = bid % 576;
        const float* srcs[3] = {Wq, Wk, Wv};
        src = srcs[part] + (size_t)l*768*768; dst = wl + (size_t)part*768*768;
        K = 768; N = 768; tj = idx % 24; ti = idx / 24;
    } else if (bid < 2304) {
        int idx = bid - 1728;
        src = Wo + (size_t)l*768*768; dst = wl + 1769472;
        K = 768; N = 768; tj = idx % 24; ti = idx / 24;
    } else if (bid < 4608) {
        int idx = bid - 2304;
        src = W1 + (size_t)l*768*3072; dst = wl + 2359296;
        K = 768; N = 3072; tj = idx % 96; ti = idx / 96;
    } else {
        int idx = bid - 4608;
        src = W2 + (size_t)l*3072*768; dst = wl + 4718592;
        K = 3072; N = 768; tj = idx % 24; ti = idx / 24;
    }
    __shared__ float tbuf[32][33];
    int tx = tid & 31, ty = tid >> 5;
    #pragma unroll
    for (int p = 0; p < 4; p++) {
        int k = ti*32 + ty + p*8, n = tj*32 + tx;
        tbuf[ty + p*8][tx] = src[(size_t)k*N + n];
    }
    __syncthreads();
    #pragma unroll
    for (int p = 0; p < 4; p++) {
        int n = tj*32 + ty + p*8, k = ti*32 + tx;
        dst[(size_t)n*K + k] = __float2bfloat16(tbuf[tx][ty + p*8]);
    }
}

// ---------------- 256x256 2-phase bf16 MFMA GEMM (tile-level drain, SAFE) ----------------
// Same passing structure as before; added T1 XCD-bijective block swizzle (m204):
// consecutive work-tiles land on the same XCD's L2 -> A/B panel reuse.
// flags: 1=bf16 out, 2=fp32 +=, 4=relu
#define MFMA_BF16(a, b, c) __builtin_amdgcn_mfma_f32_16x16x32_bf16(a, b, c, 0, 0, 0)

__global__ __launch_bounds__(512) void k_gemm256(const __hip_bfloat16* __restrict__ A,
                                                 const __hip_bfloat16* __restrict__ Bt,
                                                 const float* __restrict__ bias,
                                                 void* __restrict__ Cp,
                                                 int K, int ldb, int ldc, int flags) {
    __shared__ __align__(16) char smem[131072];
    const int tid  = threadIdx.x;
    const int lane = tid & 63;
    const int wid  = tid >> 6;
    const int wr   = wid >> 2;          // 0..1  (128-row slice)
    const int wc   = wid & 3;           // 0..3  (64-col slice)

    // T1: bijective XCD swizzle (m204). HW dispatch round-robins flat id % 8 ->
    // give each XCD a contiguous chunk of the row-major tile space.
    const int gx   = gridDim.x;
    const int nwg  = gx * gridDim.y;
    const int flat = blockIdx.y * gx + blockIdx.x;
    const int q8   = nwg >> 3, r8 = nwg & 7;
    const int xcd  = flat & 7, off8 = flat >> 3;
    const int swz  = (xcd < r8 ? xcd*(q8+1) : r8*(q8+1) + (xcd-r8)*q8) + off8;
    const int m0   = (swz / gx) * 256;
    const int n0   = (swz % gx) * 256;

    const int fr   = lane & 15, fkg = lane >> 4, sx = fr & 7;
    const int NT   = K >> 6;

    // staging: thread covers rows {0,64,128,192}+srow, 16B slot tid&7
    const int srow = tid >> 3;
    const int skc  = 8 * ((tid & 7) ^ (srow & 7));   // pre-swizzled src k-chunk

    f32x4 acc[8][4] = {};

    auto stage = [&](int kt, int buf) {
        char* base = smem + buf*65536;
        const int kk = kt*64 + skc;
        GLOAD_LDS16(A  + (size_t)(m0 +       srow) * K   + kk, base +         tid*16);
        GLOAD_LDS16(A  + (size_t)(m0 +  64 + srow) * K   + kk, base +  8192 + tid*16);
        GLOAD_LDS16(A  + (size_t)(m0 + 128 + srow) * K   + kk, base + 16384 + tid*16);
        GLOAD_LDS16(A  + (size_t)(m0 + 192 + srow) * K   + kk, base + 24576 + tid*16);
        GLOAD_LDS16(Bt + (size_t)(n0 +       srow) * ldb + kk, base + 32768 + tid*16);
        GLOAD_LDS16(Bt + (size_t)(n0 +  64 + srow) * ldb + kk, base + 40960 + tid*16);
        GLOAD_LDS16(Bt + (size_t)(n0 + 128 + srow) * ldb + kk, base + 49152 + tid*16);
        GLOAD_LDS16(Bt + (size_t)(n0 + 192 + srow) * ldb + kk, base + 57344 + tid*16);
    };
    auto ldA = [&](int buf, int i, int ks) -> bf16x8 {
        int row = wr*128 + i*16 + fr;                 // row&7 == sx
        return *(const bf16x8*)(smem + buf*65536 + row*128 + (((ks*4 + fkg) ^ sx) << 4));
    };
    auto ldB = [&](int buf, int j, int ks) -> bf16x8 {
        int row = wc*64 + j*16 + fr;                  // row&7 == sx
        return *(const bf16x8*)(smem + buf*65536 + 32768 + row*128 + (((ks*4 + fkg) ^ sx) << 4));
    };

    stage(0, 0);
    __syncthreads();

    for (int kt = 0; kt < NT; ++kt) {
        const int cur = kt & 1;
        if (kt + 1 < NT) stage(kt + 1, cur ^ 1);      // issue early, drain at tile end
        bf16x8 b[4][2];
        #pragma unroll
        for (int j = 0; j < 4; j++) { b[j][0] = ldB(cur, j, 0); b[j][1] = ldB(cur, j, 1); }
        #pragma unroll
        for (int ih = 0; ih < 2; ih++) {
            bf16x8 a[4][2];
            #pragma unroll
            for (int i = 0; i < 4; i++) {
                a[i][0] = ldA(cur, ih*4 + i, 0);
                a[i][1] = ldA(cur, ih*4 + i, 1);
            }
            __builtin_amdgcn_s_setprio(1);
            #pragma unroll
            for (int i = 0; i < 4; i++)
                #pragma unroll
                for (int j = 0; j < 4; j++) {
                    acc[ih*4+i][j] = MFMA_BF16(a[i][0], b[j][0], acc[ih*4+i][j]);
                    acc[ih*4+i][j] = MFMA_BF16(a[i][1], b[j][1], acc[ih*4+i][j]);
                }
            __builtin_amdgcn_s_setprio(0);
        }
        __syncthreads();                              // staged tile kt+1 ready; WAR safe
    }

    const int colL = lane & 15, rowg = (lane >> 4) * 4;
    #pragma unroll
    for (int i = 0; i < 8; i++) {
        #pragma unroll
        for (int j = 0; j < 4; j++) {
            int col = n0 + wc*64 + j*16 + colL;
            float bv = bias ? bias[col] : 0.0f;
            #pragma unroll
            for (int r = 0; r < 4; r++) {
                int row = m0 + wr*128 + i*16 + rowg + r;
                float v = acc[i][j][r] + bv;
                if (flags & 4) v = fmaxf(v, 0.0f);
                size_t off = (size_t)row * ldc + col;
                if (flags & 1)      ((__hip_bfloat16*)Cp)[off] = __float2bfloat16(v);
                else if (flags & 2) ((float*)Cp)[off] += v;
                else                ((float*)Cp)[off] = v;
            }
        }
    }
}

// ---------------- attention (vectorized bf16x8 loads) ----------------
__global__ __launch_bounds__(256) void k_attn(const __hip_bfloat16* __restrict__ qkv,
                                              __hip_bfloat16* __restrict__ o) {
    __shared__ float qs[SEQ_][HD_], ks[SEQ_][HD_], vs[SEQ_][HD_];
    __shared__ float att[SEQ_][SEQ_];
    int blk = blockIdx.x;
    int hh  = blk % H_;
    int cbb = blk / H_;
    int t = threadIdx.x;
    if (t < 96) {                          // 12 rows x 8 chunks of 8 elems
        int s = t >> 3, c = (t & 7) * 8;
        size_t base = (size_t)(cbb*SEQ_ + s) * 2304 + hh*64 + c;
        bf16x8 q8 = *(const bf16x8*)(qkv + base);
        bf16x8 k8 = *(const bf16x8*)(qkv + base + 768);
        bf16x8 v8 = *(const bf16x8*)(qkv + base + 1536);
        #pragma unroll
        for (int j = 0; j < 8; j++) {
            qs[s][c+j] = __uint_as_float((unsigned)(unsigned short)q8[j] << 16);
            ks[s][c+j] = __uint_as_float((unsigned)(unsigned short)k8[j] << 16);
            vs[s][c+j] = __uint_as_float((unsigned)(unsigned short)v8[j] << 16);
        }
    }
    __syncthreads();
    if (t < SEQ_*SEQ_) {
        int qi = t / SEQ_, kj = t % SEQ_;
        float s = 0.f;
        #pragma unroll
        for (int d = 0; d < HD_; d++) s += qs[qi][d] * ks[kj][d];
        att[qi][kj] = s * 0.125f;
    }
    __syncthreads();
    if (t < SEQ_) {
        float mx = -1e30f;
        #pragma unroll
        for (int j = 0; j < SEQ_; j++) mx = fmaxf(mx, att[t][j]);
        float e[SEQ_]; float sum = 0.f;
        #pragma unroll
        for (int j = 0; j < SEQ_; j++) { e[j] = expf(att[t][j] - mx); sum += e[j]; }
        float inv = 1.f / sum;
        #pragma unroll
        for (int j = 0; j < SEQ_; j++) att[t][j] = e[j] * inv;
    }
    __syncthreads();
    for (int i = t; i < SEQ_*HD_; i += 256) {
        int s = i / HD_, d = i % HD_;
        float acc = 0.f;
        #pragma unroll
        for (int j = 0; j < SEQ_; j++) acc += att[s][j] * vs[j][d];
        o[(size_t)(cbb*SEQ_ + s) * 768 + hh*64 + d] = __float2bfloat16(acc);
    }
}

// ---------------- logits ----------------
__global__ __launch_bounds__(256) void k_logits(const __hip_bfloat16* __restrict__ hfin,
                                                const float* __restrict__ Wout,
                                                const float* __restrict__ bout,
                                                float* __restrict__ logits, int cb) {
    __shared__ float red[3][256];
    int blk = blockIdx.x;
    int t = threadIdx.x;
    const __hip_bfloat16* row = hfin + (size_t)blk * SEQ_ * E_;
    float a0 = 0.f, a1 = 0.f, a2 = 0.f;
    for (int e = t; e < SEQ_*E_; e += 256) {
        float x = __bfloat162float(row[e]);
        a0 += x * Wout[e*3 + 0]; a1 += x * Wout[e*3 + 1]; a2 += x * Wout[e*3 + 2];
    }
    red[0][t] = a0; red[1][t] = a1; red[2][t] = a2;
    __syncthreads();
    for (int o = 128; o > 0; o >>= 1) {
        if (t < o) { red[0][t] += red[0][t+o]; red[1][t] += red[1][t+o]; red[2][t] += red[2][t+o]; }
        __syncthreads();
    }
    if (t < 3) logits[((size_t)cb*B_ + blk)*3 + t] = red[t][0] + bout[t];
}

// ---------------- greedy matching: ONE wave, eager 2-min row cache ----------------
// Per row cache the TWO smallest keys over alive cols (m1<m2). Maintained eagerly
// at match time: if m1's col dies, promote m2 (exact: nothing lies between them);
// rescan only when both dead. Every argmin winner is valid -> exactly 128 reduce
// trips + ~O(100s) rescans, vs the old lazy scheme's extra validate-reduce per
// stale hit. Key=(costbits<<14)|(r*128+c) reproduces reference argsort tie-break.
__global__ __launch_bounds__(64) void k_match(const float* __restrict__ logits,
                                              const float* __restrict__ targets,
                                              float* __restrict__ losses) {
    __shared__ float cst[128 * 129];       // pad 129: bank (r+c)%32, 2-way max
    __shared__ float tg[128][3];
    __shared__ int mrow[128];
    int cl = blockIdx.x, lane = threadIdx.x;
    int lidx = cl + 1;
    for (int j = lane; j < 128; j += 64) {
        const float* tp = &targets[((size_t)j*L_ + (L_ - lidx)) * 3];
        tg[j][0] = tp[0]; tg[j][1] = tp[1]; tg[j][2] = tp[2];
    }
    __syncthreads();
    u64 m1[2], m2[2];
    #pragma unroll
    for (int hh = 0; hh < 2; hh++) {
        int r = lane + hh*64;
        const float* lg = &logits[(cl*B_ + r) * 3];
        float l0 = lg[0], l1 = lg[1], l2 = lg[2];
        u64 b1 = ~0ull, b2 = ~0ull;
        for (int c = 0; c < 128; c++) {
            float d0 = l0 - tg[c][0], d1 = l1 - tg[c][1], d2 = l2 - tg[c][2];
            float cc = sqrtf(d0*d0 + d1*d1 + d2*d2 + 1e-12f);
            cst[r*129 + c] = cc;
            u64 key = ((u64)__float_as_uint(cc) << 14) | (unsigned)(r*128 + c);
            if (key < b1)      { b2 = b1; b1 = key; }
            else if (key < b2) { b2 = key; }
        }
        m1[hh] = b1; m2[hh] = b2;
    }
    __syncthreads();                       // all rows of cst visible to all lanes
    u64 dead0 = 0, dead1 = 0;
    for (int match = 0; match < 128; match++) {
        // global argmin over valid row-mins (dead rows hold ~0)
        u64 b = m1[0] < m1[1] ? m1[0] : m1[1];
        #pragma unroll
        for (int o = 32; o > 0; o >>= 1) {
            u64 x = __shfl_xor(b, o, 64);
            b = x < b ? x : b;
        }
        unsigned e  = (unsigned)b & 0x3fffu;
        unsigned wi = e >> 7, wj = e & 127;
        // commit match: kill row wi, col wj
        if ((wi & 63u) == (unsigned)lane) {
            mrow[wi] = (int)wj;
            m1[wi >> 6] = ~0ull; m2[wi >> 6] = ~0ull;
        }
        if (wj < 64) dead0 |= 1ull << wj; else dead1 |= 1ull << (wj - 64);
        // eager cache maintenance
        bool need0 = false, need1 = false;
        #pragma unroll
        for (int h = 0; h < 2; h++) {
            if (m2[h] != ~0ull && ((unsigned)m2[h] & 127u) == wj) m2[h] = ~0ull;
            if (m1[h] != ~0ull && ((unsigned)m1[h] & 127u) == wj) {
                if (m2[h] != ~0ull) { m1[h] = m2[h]; m2[h] = ~0ull; }  // exact promote
                else {
                    m1[h] = ~0ull;
                    if (h == 0) need0 = true; else need1 = true;       // rescan below
                }
            }
        }
        u64 nb0 = __ballot(need0);
        u64 nb1 = __ballot(need1);
        while (nb0 | nb1) {
            int R;
            if (nb0) { R = __builtin_ctzll(nb0);      nb0 &= nb0 - 1; }
            else     { R = __builtin_ctzll(nb1) + 64; nb1 &= nb1 - 1; }
            // cooperative rescan of row R over alive cols -> fresh (p1,p2)
            float c0 = cst[R*129 + lane];
            float c1 = cst[R*129 + lane + 64];
            bool d0b = ((dead0 >> lane) & 1ull) != 0;
            bool d1b = ((dead1 >> lane) & 1ull) != 0;
            u64 k0 = d0b ? ~0ull : (((u64)__float_as_uint(c0) << 14) | (unsigned)(R*128 + lane));
            u64 k1 = d1b ? ~0ull : (((u64)__float_as_uint(c1) << 14) | (unsigned)(R*128 + lane + 64));
            u64 p1 = k0 < k1 ? k0 : k1;
            u64 p2 = k0 < k1 ? k1 : k0;
            #pragma unroll
            for (int o = 32; o > 0; o >>= 1) {
                u64 q1 = __shfl_xor(p1, o, 64);
                u64 q2 = __shfl_xor(p2, o, 64);
                u64 lo  = p1 < q1 ? p1 : q1;
                u64 hiA = p1 < q1 ? q1 : p1;
                u64 hiB = p2 < q2 ? p2 : q2;
                p1 = lo;
                p2 = hiA < hiB ? hiA : hiB;
            }
            if ((R & 63) == lane) { m1[R >> 6] = p1; m2[R >> 6] = p2; }
        }
    }
    __syncthreads();
    float a = 0.f;
    #pragma unroll
    for (int hh = 0; hh < 2; hh++) {
        int r = lane + hh*64;
        const float* lg = &logits[(cl*B_ + mrow[r]) * 3];
        float d0 = lg[0]-tg[r][0], d1 = lg[1]-tg[r][1], d2 = lg[2]-tg[r][2];
        a += d0*d0 + d1*d1 + d2*d2;
    }
    #pragma unroll
    for (int o = 32; o > 0; o >>= 1) a += __shfl_xor(a, o, 64);
    if (lane == 0) losses[cl] = a * (1.0f / (B_*3));
}

__global__ void k_final(const float* __restrict__ losses, float* __restrict__ out) {
    float s = 0.f;
    for (int i = 0; i < 15; i++) s += losses[i];
    out[0] = s * (1.0f / 15.0f);
}

extern "C" void kernel_launch(void* const* d_in, const int* in_sizes, int n_in,
                              void* d_out, int out_size, void* d_ws, size_t ws_size,
                              hipStream_t stream) {
    (void)in_sizes; (void)n_in; (void)out_size;
    const float* X       = (const float*)d_in[0];
    const float* targets = (const float*)d_in[1];
    const float* omegas  = (const float*)d_in[2];
    const float* phases  = (const float*)d_in[3];
    const int*   perms   = (const int*)d_in[4];
    const float* Wq  = (const float*)d_in[5];
    const float* bq  = (const float*)d_in[6];
    const float* Wk  = (const float*)d_in[7];
    const float* bk  = (const float*)d_in[8];
    const float* Wv  = (const float*)d_in[9];
    const float* bv  = (const float*)d_in[10];
    const float* Wo  = (const float*)d_in[11];
    const float* bo  = (const float*)d_in[12];
    const float* ln1g = (const float*)d_in[13];
    const float* ln1b = (const float*)d_in[14];
    const float* ln2g = (const float*)d_in[15];
    const float* ln2b = (const float*)d_in[16];
    const float* W1  = (const float*)d_in[17];
    const float* b1f = (const float*)d_in[18];
    const float* W2  = (const float*)d_in[19];
    const float* b2f = (const float*)d_in[20];
    const float* lnfg = (const float*)d_in[21];
    const float* lnfb = (const float*)d_in[22];
    const float* Wout = (const float*)d_in[23];
    const float* bout = (const float*)d_in[24];

    // ws_size constant across calls -> branches are call-invariant (graph-safe).
    int CL; bool hoist;
    if (ws_size >= 263000000ull)      { CL = 15; hoist = false; }
    else if (ws_size >= 169000000ull) { CL = 5;  hoist = true;  }
    else                              { CL = 5;  hoist = false; }
    int M = CL * B_ * SEQ_;
    bool perLayerCvt = (CL == 15) || !hoist;

    char* wsb = (char*)d_ws;
    size_t off = 0;
    auto alloc = [&](size_t bytes) {
        char* p = wsb + off;
        off += (bytes + 255) & ~(size_t)255;
        return p;
    };
    float*          x      = (float*)alloc((size_t)M*E_*4);
    __hip_bfloat16* h      = (__hip_bfloat16*)alloc((size_t)M*E_*2);
    __hip_bfloat16* qkvh   = (__hip_bfloat16*)alloc((size_t)M*3072*2);  // qkv(2304) | ffn hidden(3072)
    __hip_bfloat16* wl     = (__hip_bfloat16*)alloc((hoist ? 6 : 1) * (size_t)WLS*2);
    float*          bqkv   = (float*)alloc((hoist ? 6 : 1) * (size_t)BQS*4);
    float*          logits = (float*)alloc(23040);
    float*          losses = (float*)alloc(64);

    if (hoist)
        k_cvt<<<6*6913, 256, 0, stream>>>(Wq, Wk, Wv, Wo, W1, W2, bq, bk, bv, wl, bqkv, 0);

    dim3 gQKV(2304/256, M/256);
    dim3 gF1 (3072/256, M/256);
    dim3 gN  (768/256,  M/256);
    dim3 gLN (M/4);

    for (int cb = 0; cb < 15; cb += CL) {
        k_x0<<<(M*E_)/256, 256, 0, stream>>>(X, targets, perms, omegas, phases, x, cb, M);
        for (int l = 0; l < NL_; l++) {
            __hip_bfloat16* wlp = hoist ? wl + (size_t)l*WLS : wl;
            float*          bqp = hoist ? bqkv + l*BQS : bqkv;
            if (perLayerCvt)
                k_cvt<<<6913, 256, 0, stream>>>(Wq, Wk, Wv, Wo, W1, W2, bq, bk, bv, wlp, bqp, l);
            k_ln<<<gLN, 256, 0, stream>>>(x, ln1g + l*E_, ln1b + l*E_, h);
            k_gemm256<<<gQKV, 512, 0, stream>>>(h, wlp, bqp, qkvh, 768, 768, 2304, 1);
            k_attn<<<CL*B_*H_, 256, 0, stream>>>(qkvh, h);
            k_gemm256<<<gN, 512, 0, stream>>>(h, wlp + 1769472, bo + l*E_, x,
                                              768, 768, 768, 2);
            k_ln<<<gLN, 256, 0, stream>>>(x, ln2g + l*E_, ln2b + l*E_, h);
            k_gemm256<<<gF1, 512, 0, stream>>>(h, wlp + 2359296, b1f + l*3072, qkvh,
                                               768, 768, 3072, 1|4);
            k_gemm256<<<gN, 512, 0, stream>>>(qkvh, wlp + 4718592, b2f + l*E_, x,
                                              3072, 3072, 768, 2);
        }
        k_ln<<<gLN, 256, 0, stream>>>(x, lnfg, lnfb, h);
        k_logits<<<CL*B_, 256, 0, stream>>>(h, Wout, bout, logits, cb);
    }
    k_match<<<15, 64, 0, stream>>>(logits, targets, losses);
    k_final<<<1, 1, 0, stream>>>(losses, (float*)d_out);
}

// Round 6
// 4554.573 us; speedup vs baseline: 1.1369x; 1.1369x over previous
//
#include <hip/hip_runtime.h>
#include <hip/hip_bf16.h>
#include <math.h>

#define B_   128
#define L_   16
#define E_   768
#define D_   384
#define H_   12
#define HD_  64
#define NL_  6
#define SEQ_ 12
#define LN_EPS 0.001f
#define WLS   7077888               // bf16 elems per layer weight pack
#define BQS   2304

typedef __attribute__((ext_vector_type(8))) short bf16x8;
typedef __attribute__((ext_vector_type(4))) float f32x4;
typedef unsigned long long u64;

#define GLOAD_LDS16(g, l) \
    __builtin_amdgcn_global_load_lds((__attribute__((address_space(1))) const void*)(g), \
                                     (__attribute__((address_space(3))) void*)(l), 16, 0, 0)

// ---------------- build x0 for CL lidx starting at cb (cos inlined) ----------------
__global__ __launch_bounds__(256) void k_x0(const float* __restrict__ X,
                                            const float* __restrict__ targets,
                                            const int* __restrict__ perms,
                                            const float* __restrict__ om,
                                            const float* __restrict__ ph,
                                            float* __restrict__ x, int cb, int ntok) {
    int i = blockIdx.x * 256 + threadIdx.x;
    if (i >= ntok*E_) return;
    int e   = i % E_;
    int tok = i / E_;
    int s   = tok % SEQ_;
    int bi  = (tok / SEQ_) % B_;
    int c   = tok / (SEQ_*B_);
    int cl  = cb + c;
    int lidx = cl + 1;
    int pb  = perms[cl*B_ + bi];
    float val;
    if (s < 3) {
        int t  = (e < D_) ? (L_ - lidx) : (L_ - lidx - 1);
        int dd = (e < D_) ? e : (e - D_);
        float xv = X[(pb*L_ + t)*3 + s];
        val = cosf(xv * om[s*D_ + dd] + ph[s*D_ + dd]);
    } else if (s < 6) {
        int t = (17 - lidx) & 15;
        val = targets[(pb*L_ + t)*3 + (s - 3)];
    } else {
        val = (float)(L_ - lidx);
    }
    x[i] = val;
}

// ---------------- LayerNorm: one wave per token, no barriers ----------------
__global__ __launch_bounds__(256) void k_ln(const float* __restrict__ x,
                                            const float* __restrict__ g,
                                            const float* __restrict__ b,
                                            __hip_bfloat16* __restrict__ h) {
    int gi = blockIdx.x * 256 + threadIdx.x;
    int tok = gi >> 6, lane = gi & 63;
    const float4* xr = (const float4*)(x + (size_t)tok * E_);
    float4 v0 = xr[lane], v1 = xr[lane + 64], v2 = xr[lane + 128];
    float s = v0.x+v0.y+v0.z+v0.w + v1.x+v1.y+v1.z+v1.w + v2.x+v2.y+v2.z+v2.w;
    #pragma unroll
    for (int o = 32; o > 0; o >>= 1) s += __shfl_xor(s, o, 64);
    float mu = s * (1.0f / E_);
    v0.x-=mu; v0.y-=mu; v0.z-=mu; v0.w-=mu;
    v1.x-=mu; v1.y-=mu; v1.z-=mu; v1.w-=mu;
    v2.x-=mu; v2.y-=mu; v2.z-=mu; v2.w-=mu;
    float q = v0.x*v0.x+v0.y*v0.y+v0.z*v0.z+v0.w*v0.w
            + v1.x*v1.x+v1.y*v1.y+v1.z*v1.z+v1.w*v1.w
            + v2.x*v2.x+v2.y*v2.y+v2.z*v2.z+v2.w*v2.w;
    #pragma unroll
    for (int o = 32; o > 0; o >>= 1) q += __shfl_xor(q, o, 64);
    float rstd = rsqrtf(q * (1.0f / E_) + LN_EPS);
    const float4* g4 = (const float4*)g;
    const float4* b4 = (const float4*)b;
    ushort4* h4 = (ushort4*)(h + (size_t)tok * E_);
    #pragma unroll
    for (int k = 0; k < 3; k++) {
        float4 v = (k == 0) ? v0 : (k == 1) ? v1 : v2;
        float4 gg = g4[lane + k*64], bb = b4[lane + k*64];
        ushort4 o;
        o.x = __bfloat16_as_ushort(__float2bfloat16(v.x * rstd * gg.x + bb.x));
        o.y = __bfloat16_as_ushort(__float2bfloat16(v.y * rstd * gg.y + bb.y));
        o.z = __bfloat16_as_ushort(__float2bfloat16(v.z * rstd * gg.z + bb.z));
        o.w = __bfloat16_as_ushort(__float2bfloat16(v.w * rstd * gg.w + bb.w));
        h4[lane + k*64] = o;
    }
}

// ---------------- weight transpose+convert fp32[K][N] -> bf16[N][K], nl layers ----------------
__global__ __launch_bounds__(256) void k_cvt(const float* __restrict__ Wq,
                                             const float* __restrict__ Wk,
                                             const float* __restrict__ Wv,
                                             const float* __restrict__ Wo,
                                             const float* __restrict__ W1,
                                             const float* __restrict__ W2,
                                             const float* __restrict__ bq,
                                             const float* __restrict__ bk,
                                             const float* __restrict__ bv,
                                             __hip_bfloat16* __restrict__ wl0,
                                             float* __restrict__ bqkv0, int lbase) {
    int bid = blockIdx.x;
    int l   = lbase + bid / 6913;
    bid %= 6913;
    __hip_bfloat16* wl = wl0 + (size_t)(l - lbase) * WLS;
    float* bqkv = bqkv0 + (l - lbase) * BQS;
    int tid = threadIdx.x;
    if (bid == 6912) {
        for (int i = tid; i < 2304; i += 256) {
            float v = (i < 768) ? bq[l*768 + i] : (i < 1536) ? bk[l*768 + i - 768]
                                                             : bv[l*768 + i - 1536];
            bqkv[i] = v;
        }
        return;
    }
    const float* src; __hip_bfloat16* dst; int K, N, ti, tj;
    if (bid < 1728) {
        int part = bid / 576, idx = bid % 576;
        const float* srcs[3] = {Wq, Wk, Wv};
        src = srcs[part] + (size_t)l*768*768; dst = wl + (size_t)part*768*768;
        K = 768; N = 768; tj = idx % 24; ti = idx / 24;
    } else if (bid < 2304) {
        int idx = bid - 1728;
        src = Wo + (size_t)l*768*768; dst = wl + 1769472;
        K = 768; N = 768; tj = idx % 24; ti = idx / 24;
    } else if (bid < 4608) {
        int idx = bid - 2304;
        src = W1 + (size_t)l*768*3072; dst = wl + 2359296;
        K = 768; N = 3072; tj = idx % 96; ti = idx / 96;
    } else {
        int idx = bid - 4608;
        src = W2 + (size_t)l*3072*768; dst = wl + 4718592;
        K = 3072; N = 768; tj = idx % 24; ti = idx / 24;
    }
    __shared__ float tbuf[32][33];
    int tx = tid & 31, ty = tid >> 5;
    #pragma unroll
    for (int p = 0; p < 4; p++) {
        int k = ti*32 + ty + p*8, n = tj*32 + tx;
        tbuf[ty + p*8][tx] = src[(size_t)k*N + n];
    }
    __syncthreads();
    #pragma unroll
    for (int p = 0; p < 4; p++) {
        int n = tj*32 + ty + p*8, k = ti*32 + tx;
        dst[(size_t)n*K + k] = __float2bfloat16(tbuf[tx][ty + p*8]);
    }
}

#define MFMA_BF16(a, b, c) __builtin_amdgcn_mfma_f32_16x16x32_bf16(a, b, c, 0, 0, 0)

// ---------------- 256x256 2-phase bf16 MFMA GEMM (tile-level drain, SAFE) ----------------
// flags: 1=bf16 out, 2=fp32 +=, 4=relu
__global__ __launch_bounds__(512) void k_gemm256(const __hip_bfloat16* __restrict__ A,
                                                 const __hip_bfloat16* __restrict__ Bt,
                                                 const float* __restrict__ bias,
                                                 void* __restrict__ Cp,
                                                 int K, int ldb, int ldc, int flags) {
    __shared__ __align__(16) char smem[131072];
    const int tid  = threadIdx.x;
    const int lane = tid & 63;
    const int wid  = tid >> 6;
    const int wr   = wid >> 2;          // 0..1  (128-row slice)
    const int wc   = wid & 3;           // 0..3  (64-col slice)

    // T1: bijective XCD swizzle (m204)
    const int gx   = gridDim.x;
    const int nwg  = gx * gridDim.y;
    const int flat = blockIdx.y * gx + blockIdx.x;
    const int q8   = nwg >> 3, r8 = nwg & 7;
    const int xcd  = flat & 7, off8 = flat >> 3;
    const int swz  = (xcd < r8 ? xcd*(q8+1) : r8*(q8+1) + (xcd-r8)*q8) + off8;
    const int m0   = (swz / gx) * 256;
    const int n0   = (swz % gx) * 256;

    const int fr   = lane & 15, fkg = lane >> 4, sx = fr & 7;
    const int NT   = K >> 6;

    const int srow = tid >> 3;
    const int skc  = 8 * ((tid & 7) ^ (srow & 7));   // pre-swizzled src k-chunk

    f32x4 acc[8][4] = {};

    auto stage = [&](int kt, int buf) {
        char* base = smem + buf*65536;
        const int kk = kt*64 + skc;
        GLOAD_LDS16(A  + (size_t)(m0 +       srow) * K   + kk, base +         tid*16);
        GLOAD_LDS16(A  + (size_t)(m0 +  64 + srow) * K   + kk, base +  8192 + tid*16);
        GLOAD_LDS16(A  + (size_t)(m0 + 128 + srow) * K   + kk, base + 16384 + tid*16);
        GLOAD_LDS16(A  + (size_t)(m0 + 192 + srow) * K   + kk, base + 24576 + tid*16);
        GLOAD_LDS16(Bt + (size_t)(n0 +       srow) * ldb + kk, base + 32768 + tid*16);
        GLOAD_LDS16(Bt + (size_t)(n0 +  64 + srow) * ldb + kk, base + 40960 + tid*16);
        GLOAD_LDS16(Bt + (size_t)(n0 + 128 + srow) * ldb + kk, base + 49152 + tid*16);
        GLOAD_LDS16(Bt + (size_t)(n0 + 192 + srow) * ldb + kk, base + 57344 + tid*16);
    };
    auto ldA = [&](int buf, int i, int ks) -> bf16x8 {
        int row = wr*128 + i*16 + fr;                 // row&7 == sx
        return *(const bf16x8*)(smem + buf*65536 + row*128 + (((ks*4 + fkg) ^ sx) << 4));
    };
    auto ldB = [&](int buf, int j, int ks) -> bf16x8 {
        int row = wc*64 + j*16 + fr;                  // row&7 == sx
        return *(const bf16x8*)(smem + buf*65536 + 32768 + row*128 + (((ks*4 + fkg) ^ sx) << 4));
    };

    stage(0, 0);
    __syncthreads();

    for (int kt = 0; kt < NT; ++kt) {
        const int cur = kt & 1;
        if (kt + 1 < NT) stage(kt + 1, cur ^ 1);      // issue early, drain at tile end
        bf16x8 b[4][2];
        #pragma unroll
        for (int j = 0; j < 4; j++) { b[j][0] = ldB(cur, j, 0); b[j][1] = ldB(cur, j, 1); }
        #pragma unroll
        for (int ih = 0; ih < 2; ih++) {
            bf16x8 a[4][2];
            #pragma unroll
            for (int i = 0; i < 4; i++) {
                a[i][0] = ldA(cur, ih*4 + i, 0);
                a[i][1] = ldA(cur, ih*4 + i, 1);
            }
            __builtin_amdgcn_s_setprio(1);
            #pragma unroll
            for (int i = 0; i < 4; i++)
                #pragma unroll
                for (int j = 0; j < 4; j++) {
                    acc[ih*4+i][j] = MFMA_BF16(a[i][0], b[j][0], acc[ih*4+i][j]);
                    acc[ih*4+i][j] = MFMA_BF16(a[i][1], b[j][1], acc[ih*4+i][j]);
                }
            __builtin_amdgcn_s_setprio(0);
        }
        __syncthreads();                              // staged tile kt+1 ready; WAR safe
    }

    const int colL = lane & 15, rowg = (lane >> 4) * 4;
    #pragma unroll
    for (int i = 0; i < 8; i++) {
        #pragma unroll
        for (int j = 0; j < 4; j++) {
            int col = n0 + wc*64 + j*16 + colL;
            float bv = bias ? bias[col] : 0.0f;
            #pragma unroll
            for (int r = 0; r < 4; r++) {
                int row = m0 + wr*128 + i*16 + rowg + r;
                float v = acc[i][j][r] + bv;
                if (flags & 4) v = fmaxf(v, 0.0f);
                size_t off = (size_t)row * ldc + col;
                if (flags & 1)      ((__hip_bfloat16*)Cp)[off] = __float2bfloat16(v);
                else if (flags & 2) ((float*)Cp)[off] += v;
                else                ((float*)Cp)[off] = v;
            }
        }
    }
}

// ---------------- 128x128 2-phase bf16 MFMA GEMM (2 blocks/CU, for small N) ----------------
// Same schedule/swizzle/K-order as k_gemm256 (bit-identical accumulation), but
// 256 thr = 4 waves (2x2), 64 KiB LDS dbuf -> 2 blocks/CU: smooth tails for the
// N=768 GEMMs (grid 1080 blocks vs 270) + cross-block stage/compute overlap.
__global__ __launch_bounds__(256) void k_gemm128(const __hip_bfloat16* __restrict__ A,
                                                 const __hip_bfloat16* __restrict__ Bt,
                                                 const float* __restrict__ bias,
                                                 void* __restrict__ Cp,
                                                 int K, int ldb, int ldc, int flags) {
    __shared__ __align__(16) char smem[65536];
    const int tid  = threadIdx.x;
    const int lane = tid & 63;
    const int wid  = tid >> 6;
    const int wr   = wid >> 1;          // 0..1  (64-row slice)
    const int wc   = wid & 1;           // 0..1  (64-col slice)

    const int gx   = gridDim.x;
    const int nwg  = gx * gridDim.y;
    const int flat = blockIdx.y * gx + blockIdx.x;
    const int q8   = nwg >> 3, r8 = nwg & 7;
    const int xcd  = flat & 7, off8 = flat >> 3;
    const int swz  = (xcd < r8 ? xcd*(q8+1) : r8*(q8+1) + (xcd-r8)*q8) + off8;
    const int m0   = (swz / gx) * 128;
    const int n0   = (swz % gx) * 128;

    const int fr   = lane & 15, fkg = lane >> 4, sx = fr & 7;
    const int NT   = K >> 6;

    const int srow = tid >> 3;          // 0..31
    const int skc  = 8 * ((tid & 7) ^ (srow & 7));

    f32x4 acc[4][4] = {};

    auto stage = [&](int kt, int buf) {
        char* base = smem + buf*32768;
        const int kk = kt*64 + skc;
        GLOAD_LDS16(A  + (size_t)(m0 +      srow) * K   + kk, base +         tid*16);
        GLOAD_LDS16(A  + (size_t)(m0 + 32 + srow) * K   + kk, base +  4096 + tid*16);
        GLOAD_LDS16(A  + (size_t)(m0 + 64 + srow) * K   + kk, base +  8192 + tid*16);
        GLOAD_LDS16(A  + (size_t)(m0 + 96 + srow) * K   + kk, base + 12288 + tid*16);
        GLOAD_LDS16(Bt + (size_t)(n0 +      srow) * ldb + kk, base + 16384 + tid*16);
        GLOAD_LDS16(Bt + (size_t)(n0 + 32 + srow) * ldb + kk, base + 20480 + tid*16);
        GLOAD_LDS16(Bt + (size_t)(n0 + 64 + srow) * ldb + kk, base + 24576 + tid*16);
        GLOAD_LDS16(Bt + (size_t)(n0 + 96 + srow) * ldb + kk, base + 28672 + tid*16);
    };
    auto ldA = [&](int buf, int i, int ks) -> bf16x8 {
        int row = wr*64 + i*16 + fr;                  // row&7 == sx
        return *(const bf16x8*)(smem + buf*32768 + row*128 + (((ks*4 + fkg) ^ sx) << 4));
    };
    auto ldB = [&](int buf, int j, int ks) -> bf16x8 {
        int row = wc*64 + j*16 + fr;                  // row&7 == sx
        return *(const bf16x8*)(smem + buf*32768 + 16384 + row*128 + (((ks*4 + fkg) ^ sx) << 4));
    };

    stage(0, 0);
    __syncthreads();

    for (int kt = 0; kt < NT; ++kt) {
        const int cur = kt & 1;
        if (kt + 1 < NT) stage(kt + 1, cur ^ 1);
        bf16x8 b[4][2], a[4][2];
        #pragma unroll
        for (int j = 0; j < 4; j++) { b[j][0] = ldB(cur, j, 0); b[j][1] = ldB(cur, j, 1); }
        #pragma unroll
        for (int i = 0; i < 4; i++) { a[i][0] = ldA(cur, i, 0); a[i][1] = ldA(cur, i, 1); }
        __builtin_amdgcn_s_setprio(1);
        #pragma unroll
        for (int i = 0; i < 4; i++)
            #pragma unroll
            for (int j = 0; j < 4; j++) {
                acc[i][j] = MFMA_BF16(a[i][0], b[j][0], acc[i][j]);
                acc[i][j] = MFMA_BF16(a[i][1], b[j][1], acc[i][j]);
            }
        __builtin_amdgcn_s_setprio(0);
        __syncthreads();
    }

    const int colL = lane & 15, rowg = (lane >> 4) * 4;
    #pragma unroll
    for (int i = 0; i < 4; i++) {
        #pragma unroll
        for (int j = 0; j < 4; j++) {
            int col = n0 + wc*64 + j*16 + colL;
            float bv = bias ? bias[col] : 0.0f;
            #pragma unroll
            for (int r = 0; r < 4; r++) {
                int row = m0 + wr*64 + i*16 + rowg + r;
                float v = acc[i][j][r] + bv;
                if (flags & 4) v = fmaxf(v, 0.0f);
                size_t off = (size_t)row * ldc + col;
                if (flags & 1)      ((__hip_bfloat16*)Cp)[off] = __float2bfloat16(v);
                else if (flags & 2) ((float*)Cp)[off] += v;
                else                ((float*)Cp)[off] = v;
            }
        }
    }
}

// ---------------- attention (vectorized bf16x8 loads) ----------------
__global__ __launch_bounds__(256) void k_attn(const __hip_bfloat16* __restrict__ qkv,
                                              __hip_bfloat16* __restrict__ o) {
    __shared__ float qs[SEQ_][HD_], ks[SEQ_][HD_], vs[SEQ_][HD_];
    __shared__ float att[SEQ_][SEQ_];
    int blk = blockIdx.x;
    int hh  = blk % H_;
    int cbb = blk / H_;
    int t = threadIdx.x;
    if (t < 96) {                          // 12 rows x 8 chunks of 8 elems
        int s = t >> 3, c = (t & 7) * 8;
        size_t base = (size_t)(cbb*SEQ_ + s) * 2304 + hh*64 + c;
        bf16x8 q8 = *(const bf16x8*)(qkv + base);
        bf16x8 k8 = *(const bf16x8*)(qkv + base + 768);
        bf16x8 v8 = *(const bf16x8*)(qkv + base + 1536);
        #pragma unroll
        for (int j = 0; j < 8; j++) {
            qs[s][c+j] = __uint_as_float((unsigned)(unsigned short)q8[j] << 16);
            ks[s][c+j] = __uint_as_float((unsigned)(unsigned short)k8[j] << 16);
            vs[s][c+j] = __uint_as_float((unsigned)(unsigned short)v8[j] << 16);
        }
    }
    __syncthreads();
    if (t < SEQ_*SEQ_) {
        int qi = t / SEQ_, kj = t % SEQ_;
        float s = 0.f;
        #pragma unroll
        for (int d = 0; d < HD_; d++) s += qs[qi][d] * ks[kj][d];
        att[qi][kj] = s * 0.125f;
    }
    __syncthreads();
    if (t < SEQ_) {
        float mx = -1e30f;
        #pragma unroll
        for (int j = 0; j < SEQ_; j++) mx = fmaxf(mx, att[t][j]);
        float e[SEQ_]; float sum = 0.f;
        #pragma unroll
        for (int j = 0; j < SEQ_; j++) { e[j] = expf(att[t][j] - mx); sum += e[j]; }
        float inv = 1.f / sum;
        #pragma unroll
        for (int j = 0; j < SEQ_; j++) att[t][j] = e[j] * inv;
    }
    __syncthreads();
    for (int i = t; i < SEQ_*HD_; i += 256) {
        int s = i / HD_, d = i % HD_;
        float acc = 0.f;
        #pragma unroll
        for (int j = 0; j < SEQ_; j++) acc += att[s][j] * vs[j][d];
        o[(size_t)(cbb*SEQ_ + s) * 768 + hh*64 + d] = __float2bfloat16(acc);
    }
}

// ---------------- logits ----------------
__global__ __launch_bounds__(256) void k_logits(const __hip_bfloat16* __restrict__ hfin,
                                                const float* __restrict__ Wout,
                                                const float* __restrict__ bout,
                                                float* __restrict__ logits, int cb) {
    __shared__ float red[3][256];
    int blk = blockIdx.x;
    int t = threadIdx.x;
    const __hip_bfloat16* row = hfin + (size_t)blk * SEQ_ * E_;
    float a0 = 0.f, a1 = 0.f, a2 = 0.f;
    for (int e = t; e < SEQ_*E_; e += 256) {
        float x = __bfloat162float(row[e]);
        a0 += x * Wout[e*3 + 0]; a1 += x * Wout[e*3 + 1]; a2 += x * Wout[e*3 + 2];
    }
    red[0][t] = a0; red[1][t] = a1; red[2][t] = a2;
    __syncthreads();
    for (int o = 128; o > 0; o >>= 1) {
        if (t < o) { red[0][t] += red[0][t+o]; red[1][t] += red[1][t+o]; red[2][t] += red[2][t+o]; }
        __syncthreads();
    }
    if (t < 3) logits[((size_t)cb*B_ + blk)*3 + t] = red[t][0] + bout[t];
}

// ---------------- greedy matching: ONE wave, lazy-rescan row-cache ----------------
// (round-4 version: measured 355 us; eager 2-min variant regressed to 501 us)
__global__ __launch_bounds__(64) void k_match(const float* __restrict__ logits,
                                              const float* __restrict__ targets,
                                              float* __restrict__ losses) {
    __shared__ float cst[128 * 129];       // pad 129: bank (r+c)%32, 2-way max
    __shared__ float tg[128][3];
    __shared__ int mrow[128];
    int cl = blockIdx.x, lane = threadIdx.x;
    int lidx = cl + 1;
    for (int j = lane; j < 128; j += 64) {
        const float* tp = &targets[((size_t)j*L_ + (L_ - lidx)) * 3];
        tg[j][0] = tp[0]; tg[j][1] = tp[1]; tg[j][2] = tp[2];
    }
    __syncthreads();
    u64 kc[2];
    #pragma unroll
    for (int hh = 0; hh < 2; hh++) {
        int r = lane + hh*64;
        const float* lg = &logits[(cl*B_ + r) * 3];
        float l0 = lg[0], l1 = lg[1], l2 = lg[2];
        u64 best = ~0ull;
        for (int c = 0; c < 128; c++) {
            float d0 = l0 - tg[c][0], d1 = l1 - tg[c][1], d2 = l2 - tg[c][2];
            float cc = sqrtf(d0*d0 + d1*d1 + d2*d2 + 1e-12f);
            cst[r*129 + c] = cc;
            u64 key = ((u64)__float_as_uint(cc) << 14) | (unsigned)(r*128 + c);
            best = key < best ? key : best;
        }
        kc[hh] = best;
    }
    __syncthreads();                       // all rows of cst visible to all lanes
    u64 dead0 = 0, dead1 = 0;
    int done = 0;
    for (int trip = 0; trip < 16640 && done < 128; trip++) {
        u64 b = kc[0] < kc[1] ? kc[0] : kc[1];
        #pragma unroll
        for (int o = 32; o > 0; o >>= 1) {
            u64 x = __shfl_xor(b, o, 64);
            b = x < b ? x : b;
        }
        unsigned e  = (unsigned)b & 0x3fffu;
        unsigned wi = e >> 7, wj = e & 127;
        bool isDead = (((wj < 64) ? (dead0 >> wj) : (dead1 >> (wj - 64))) & 1ull) != 0;
        if (!isDead) {                     // wave-uniform branch
            if ((wi & 63u) == (unsigned)lane) {
                mrow[wi] = (int)wj;
                kc[wi >> 6] = ~0ull;
            }
            if (wj < 64) dead0 |= 1ull << wj; else dead1 |= 1ull << (wj - 64);
            done++;
        } else {                           // stale winner: rescan row wi cooperatively
            float c0 = cst[wi*129 + lane];
            float c1 = cst[wi*129 + lane + 64];
            bool d0b = ((dead0 >> lane) & 1ull) != 0;
            bool d1b = ((dead1 >> lane) & 1ull) != 0;
            u64 k0 = d0b ? ~0ull : (((u64)__float_as_uint(c0) << 14) | (unsigned)(wi*128 + lane));
            u64 k1 = d1b ? ~0ull : (((u64)__float_as_uint(c1) << 14) | (unsigned)(wi*128 + lane + 64));
            u64 nb = k0 < k1 ? k0 : k1;
            #pragma unroll
            for (int o = 32; o > 0; o >>= 1) {
                u64 x = __shfl_xor(nb, o, 64);
                nb = x < nb ? x : nb;
            }
            if ((wi & 63u) == (unsigned)lane) kc[wi >> 6] = nb;
        }
    }
    __syncthreads();
    float a = 0.f;
    #pragma unroll
    for (int hh = 0; hh < 2; hh++) {
        int r = lane + hh*64;
        const float* lg = &logits[(cl*B_ + mrow[r]) * 3];
        float d0 = lg[0]-tg[r][0], d1 = lg[1]-tg[r][1], d2 = lg[2]-tg[r][2];
        a += d0*d0 + d1*d1 + d2*d2;
    }
    #pragma unroll
    for (int o = 32; o > 0; o >>= 1) a += __shfl_xor(a, o, 64);
    if (lane == 0) losses[cl] = a * (1.0f / (B_*3));
}

__global__ void k_final(const float* __restrict__ losses, float* __restrict__ out) {
    float s = 0.f;
    for (int i = 0; i < 15; i++) s += losses[i];
    out[0] = s * (1.0f / 15.0f);
}

extern "C" void kernel_launch(void* const* d_in, const int* in_sizes, int n_in,
                              void* d_out, int out_size, void* d_ws, size_t ws_size,
                              hipStream_t stream) {
    (void)in_sizes; (void)n_in; (void)out_size;
    const float* X       = (const float*)d_in[0];
    const float* targets = (const float*)d_in[1];
    const float* omegas  = (const float*)d_in[2];
    const float* phases  = (const float*)d_in[3];
    const int*   perms   = (const int*)d_in[4];
    const float* Wq  = (const float*)d_in[5];
    const float* bq  = (const float*)d_in[6];
    const float* Wk  = (const float*)d_in[7];
    const float* bk  = (const float*)d_in[8];
    const float* Wv  = (const float*)d_in[9];
    const float* bv  = (const float*)d_in[10];
    const float* Wo  = (const float*)d_in[11];
    const float* bo  = (const float*)d_in[12];
    const float* ln1g = (const float*)d_in[13];
    const float* ln1b = (const float*)d_in[14];
    const float* ln2g = (const float*)d_in[15];
    const float* ln2b = (const float*)d_in[16];
    const float* W1  = (const float*)d_in[17];
    const float* b1f = (const float*)d_in[18];
    const float* W2  = (const float*)d_in[19];
    const float* b2f = (const float*)d_in[20];
    const float* lnfg = (const float*)d_in[21];
    const float* lnfb = (const float*)d_in[22];
    const float* Wout = (const float*)d_in[23];
    const float* bout = (const float*)d_in[24];

    // ws_size constant across calls -> branches are call-invariant (graph-safe).
    int CL; bool hoist;
    if (ws_size >= 263000000ull)      { CL = 15; hoist = false; }
    else if (ws_size >= 169000000ull) { CL = 5;  hoist = true;  }
    else                              { CL = 5;  hoist = false; }
    int M = CL * B_ * SEQ_;
    bool perLayerCvt = (CL == 15) || !hoist;

    char* wsb = (char*)d_ws;
    size_t off = 0;
    auto alloc = [&](size_t bytes) {
        char* p = wsb + off;
        off += (bytes + 255) & ~(size_t)255;
        return p;
    };
    float*          x      = (float*)alloc((size_t)M*E_*4);
    __hip_bfloat16* h      = (__hip_bfloat16*)alloc((size_t)M*E_*2);
    __hip_bfloat16* qkvh   = (__hip_bfloat16*)alloc((size_t)M*3072*2);  // qkv(2304) | ffn hidden(3072)
    __hip_bfloat16* wl     = (__hip_bfloat16*)alloc((hoist ? 6 : 1) * (size_t)WLS*2);
    float*          bqkv   = (float*)alloc((hoist ? 6 : 1) * (size_t)BQS*4);
    float*          logits = (float*)alloc(23040);
    float*          losses = (float*)alloc(64);

    if (hoist)
        k_cvt<<<6*6913, 256, 0, stream>>>(Wq, Wk, Wv, Wo, W1, W2, bq, bk, bv, wl, bqkv, 0);

    dim3 gQKV(2304/256, M/256);
    dim3 gF1 (3072/256, M/256);
    dim3 gN  (768/128,  M/128);
    dim3 gLN (M/4);

    for (int cb = 0; cb < 15; cb += CL) {
        k_x0<<<(M*E_)/256, 256, 0, stream>>>(X, targets, perms, omegas, phases, x, cb, M);
        for (int l = 0; l < NL_; l++) {
            __hip_bfloat16* wlp = hoist ? wl + (size_t)l*WLS : wl;
            float*          bqp = hoist ? bqkv + l*BQS : bqkv;
            if (perLayerCvt)
                k_cvt<<<6913, 256, 0, stream>>>(Wq, Wk, Wv, Wo, W1, W2, bq, bk, bv, wlp, bqp, l);
            k_ln<<<gLN, 256, 0, stream>>>(x, ln1g + l*E_, ln1b + l*E_, h);
            k_gemm256<<<gQKV, 512, 0, stream>>>(h, wlp, bqp, qkvh, 768, 768, 2304, 1);
            k_attn<<<CL*B_*H_, 256, 0, stream>>>(qkvh, h);
            k_gemm128<<<gN, 256, 0, stream>>>(h, wlp + 1769472, bo + l*E_, x,
                                              768, 768, 768, 2);
            k_ln<<<gLN, 256, 0, stream>>>(x, ln2g + l*E_, ln2b + l*E_, h);
            k_gemm256<<<gF1, 512, 0, stream>>>(h, wlp + 2359296, b1f + l*3072, qkvh,
                                               768, 768, 3072, 1|4);
            k_gemm128<<<gN, 256, 0, stream>>>(qkvh, wlp + 4718592, b2f + l*E_, x,
                                              3072, 3072, 768, 2);
        }
        k_ln<<<gLN, 256, 0, stream>>>(x, lnfg, lnfb, h);
        k_logits<<<CL*B_, 256, 0, stream>>>(h, Wout, bout, logits, cb);
    }
    k_match<<<15, 64, 0, stream>>>(logits, targets, losses);
    k_final<<<1, 1, 0, stream>>>(losses, (float*)d_out);
}

// Round 7
// 4514.839 us; speedup vs baseline: 1.1469x; 1.0088x over previous
//
#include <hip/hip_runtime.h>
#include <hip/hip_bf16.h>
#include <math.h>

#define B_   128
#define L_   16
#define E_   768
#define D_   384
#define H_   12
#define HD_  64
#define NL_  6
#define SEQ_ 12
#define LN_EPS 0.001f
#define WLS   7077888               // bf16 elems per layer weight pack
#define BQS   2304

typedef __attribute__((ext_vector_type(8))) short bf16x8;
typedef __attribute__((ext_vector_type(4))) float f32x4;
typedef unsigned long long u64;

#define GLOAD_LDS16(g, l) \
    __builtin_amdgcn_global_load_lds((__attribute__((address_space(1))) const void*)(g), \
                                     (__attribute__((address_space(3))) void*)(l), 16, 0, 0)

// ---------------- build x0 for CL lidx starting at cb (cos inlined) ----------------
__global__ __launch_bounds__(256) void k_x0(const float* __restrict__ X,
                                            const float* __restrict__ targets,
                                            const int* __restrict__ perms,
                                            const float* __restrict__ om,
                                            const float* __restrict__ ph,
                                            float* __restrict__ x, int cb, int ntok) {
    int i = blockIdx.x * 256 + threadIdx.x;
    if (i >= ntok*E_) return;
    int e   = i % E_;
    int tok = i / E_;
    int s   = tok % SEQ_;
    int bi  = (tok / SEQ_) % B_;
    int c   = tok / (SEQ_*B_);
    int cl  = cb + c;
    int lidx = cl + 1;
    int pb  = perms[cl*B_ + bi];
    float val;
    if (s < 3) {
        int t  = (e < D_) ? (L_ - lidx) : (L_ - lidx - 1);
        int dd = (e < D_) ? e : (e - D_);
        float xv = X[(pb*L_ + t)*3 + s];
        val = cosf(xv * om[s*D_ + dd] + ph[s*D_ + dd]);
    } else if (s < 6) {
        int t = (17 - lidx) & 15;
        val = targets[(pb*L_ + t)*3 + (s - 3)];
    } else {
        val = (float)(L_ - lidx);
    }
    x[i] = val;
}

// ---------------- LayerNorm: one wave per token, no barriers ----------------
__global__ __launch_bounds__(256) void k_ln(const float* __restrict__ x,
                                            const float* __restrict__ g,
                                            const float* __restrict__ b,
                                            __hip_bfloat16* __restrict__ h) {
    int gi = blockIdx.x * 256 + threadIdx.x;
    int tok = gi >> 6, lane = gi & 63;
    const float4* xr = (const float4*)(x + (size_t)tok * E_);
    float4 v0 = xr[lane], v1 = xr[lane + 64], v2 = xr[lane + 128];
    float s = v0.x+v0.y+v0.z+v0.w + v1.x+v1.y+v1.z+v1.w + v2.x+v2.y+v2.z+v2.w;
    #pragma unroll
    for (int o = 32; o > 0; o >>= 1) s += __shfl_xor(s, o, 64);
    float mu = s * (1.0f / E_);
    v0.x-=mu; v0.y-=mu; v0.z-=mu; v0.w-=mu;
    v1.x-=mu; v1.y-=mu; v1.z-=mu; v1.w-=mu;
    v2.x-=mu; v2.y-=mu; v2.z-=mu; v2.w-=mu;
    float q = v0.x*v0.x+v0.y*v0.y+v0.z*v0.z+v0.w*v0.w
            + v1.x*v1.x+v1.y*v1.y+v1.z*v1.z+v1.w*v1.w
            + v2.x*v2.x+v2.y*v2.y+v2.z*v2.z+v2.w*v2.w;
    #pragma unroll
    for (int o = 32; o > 0; o >>= 1) q += __shfl_xor(q, o, 64);
    float rstd = rsqrtf(q * (1.0f / E_) + LN_EPS);
    const float4* g4 = (const float4*)g;
    const float4* b4 = (const float4*)b;
    ushort4* h4 = (ushort4*)(h + (size_t)tok * E_);
    #pragma unroll
    for (int k = 0; k < 3; k++) {
        float4 v = (k == 0) ? v0 : (k == 1) ? v1 : v2;
        float4 gg = g4[lane + k*64], bb = b4[lane + k*64];
        ushort4 o;
        o.x = __bfloat16_as_ushort(__float2bfloat16(v.x * rstd * gg.x + bb.x));
        o.y = __bfloat16_as_ushort(__float2bfloat16(v.y * rstd * gg.y + bb.y));
        o.z = __bfloat16_as_ushort(__float2bfloat16(v.z * rstd * gg.z + bb.z));
        o.w = __bfloat16_as_ushort(__float2bfloat16(v.w * rstd * gg.w + bb.w));
        h4[lane + k*64] = o;
    }
}

// ---------------- weight transpose+convert fp32[K][N] -> bf16[N][K], nl layers ----------------
__global__ __launch_bounds__(256) void k_cvt(const float* __restrict__ Wq,
                                             const float* __restrict__ Wk,
                                             const float* __restrict__ Wv,
                                             const float* __restrict__ Wo,
                                             const float* __restrict__ W1,
                                             const float* __restrict__ W2,
                                             const float* __restrict__ bq,
                                             const float* __restrict__ bk,
                                             const float* __restrict__ bv,
                                             __hip_bfloat16* __restrict__ wl0,
                                             float* __restrict__ bqkv0, int lbase) {
    int bid = blockIdx.x;
    int l   = lbase + bid / 6913;
    bid %= 6913;
    __hip_bfloat16* wl = wl0 + (size_t)(l - lbase) * WLS;
    float* bqkv = bqkv0 + (l - lbase) * BQS;
    int tid = threadIdx.x;
    if (bid == 6912) {
        for (int i = tid; i < 2304; i += 256) {
            float v = (i < 768) ? bq[l*768 + i] : (i < 1536) ? bk[l*768 + i - 768]
                                                             : bv[l*768 + i - 1536];
            bqkv[i] = v;
        }
        return;
    }
    const float* src; __hip_bfloat16* dst; int K, N, ti, tj;
    if (bid < 1728) {
        int part = bid / 576, idx = bid % 576;
        const float* srcs[3] = {Wq, Wk, Wv};
        src = srcs[part] + (size_t)l*768*768; dst = wl + (size_t)part*768*768;
        K = 768; N = 768; tj = idx % 24; ti = idx / 24;
    } else if (bid < 2304) {
        int idx = bid - 1728;
        src = Wo + (size_t)l*768*768; dst = wl + 1769472;
        K = 768; N = 768; tj = idx % 24; ti = idx / 24;
    } else if (bid < 4608) {
        int idx = bid - 2304;
        src = W1 + (size_t)l*768*3072; dst = wl + 2359296;
        K = 768; N = 3072; tj = idx % 96; ti = idx / 96;
    } else {
        int idx = bid - 4608;
        src = W2 + (size_t)l*3072*768; dst = wl + 4718592;
        K = 3072; N = 768; tj = idx % 24; ti = idx / 24;
    }
    __shared__ float tbuf[32][33];
    int tx = tid & 31, ty = tid >> 5;
    #pragma unroll
    for (int p = 0; p < 4; p++) {
        int k = ti*32 + ty + p*8, n = tj*32 + tx;
        tbuf[ty + p*8][tx] = src[(size_t)k*N + n];
    }
    __syncthreads();
    #pragma unroll
    for (int p = 0; p < 4; p++) {
        int n = tj*32 + ty + p*8, k = ti*32 + tx;
        dst[(size_t)n*K + k] = __float2bfloat16(tbuf[tx][ty + p*8]);
    }
}

#define MFMA_BF16(a, b, c) __builtin_amdgcn_mfma_f32_16x16x32_bf16(a, b, c, 0, 0, 0)

// ---------------- 128x128 2-phase bf16 MFMA GEMM (2 blocks/CU) ----------------
// Measured round 6: moving N=768 GEMMs here from 256x256 won 543 us (occupancy/
// tail mechanism). Now used for ALL GEMMs. 256 thr = 4 waves (2x2), 64 KiB LDS
// dbuf -> 2 blocks/CU. Stage-all -> __syncthreads only (no counted vmcnt: the
// quadrant/counted variant failed on HW, rounds 1-2). XOR chunk swizzle on the
// GLOBAL source; LDS dest linear. K in ascending 64-chunks, ks0->ks1 per tile:
// bit-identical accumulation across all GEMM variants.
// flags: 1=bf16 out, 2=fp32 +=, 4=relu
__global__ __launch_bounds__(256) void k_gemm128(const __hip_bfloat16* __restrict__ A,
                                                 const __hip_bfloat16* __restrict__ Bt,
                                                 const float* __restrict__ bias,
                                                 void* __restrict__ Cp,
                                                 int K, int ldb, int ldc, int flags) {
    __shared__ __align__(16) char smem[65536];
    const int tid  = threadIdx.x;
    const int lane = tid & 63;
    const int wid  = tid >> 6;
    const int wr   = wid >> 1;          // 0..1  (64-row slice)
    const int wc   = wid & 1;           // 0..1  (64-col slice)

    // T1: bijective XCD swizzle (m204)
    const int gx   = gridDim.x;
    const int nwg  = gx * gridDim.y;
    const int flat = blockIdx.y * gx + blockIdx.x;
    const int q8   = nwg >> 3, r8 = nwg & 7;
    const int xcd  = flat & 7, off8 = flat >> 3;
    const int swz  = (xcd < r8 ? xcd*(q8+1) : r8*(q8+1) + (xcd-r8)*q8) + off8;
    const int m0   = (swz / gx) * 128;
    const int n0   = (swz % gx) * 128;

    const int fr   = lane & 15, fkg = lane >> 4, sx = fr & 7;
    const int NT   = K >> 6;

    const int srow = tid >> 3;          // 0..31
    const int skc  = 8 * ((tid & 7) ^ (srow & 7));

    f32x4 acc[4][4] = {};

    auto stage = [&](int kt, int buf) {
        char* base = smem + buf*32768;
        const int kk = kt*64 + skc;
        GLOAD_LDS16(A  + (size_t)(m0 +      srow) * K   + kk, base +         tid*16);
        GLOAD_LDS16(A  + (size_t)(m0 + 32 + srow) * K   + kk, base +  4096 + tid*16);
        GLOAD_LDS16(A  + (size_t)(m0 + 64 + srow) * K   + kk, base +  8192 + tid*16);
        GLOAD_LDS16(A  + (size_t)(m0 + 96 + srow) * K   + kk, base + 12288 + tid*16);
        GLOAD_LDS16(Bt + (size_t)(n0 +      srow) * ldb + kk, base + 16384 + tid*16);
        GLOAD_LDS16(Bt + (size_t)(n0 + 32 + srow) * ldb + kk, base + 20480 + tid*16);
        GLOAD_LDS16(Bt + (size_t)(n0 + 64 + srow) * ldb + kk, base + 24576 + tid*16);
        GLOAD_LDS16(Bt + (size_t)(n0 + 96 + srow) * ldb + kk, base + 28672 + tid*16);
    };
    auto ldA = [&](int buf, int i, int ks) -> bf16x8 {
        int row = wr*64 + i*16 + fr;                  // row&7 == sx
        return *(const bf16x8*)(smem + buf*32768 + row*128 + (((ks*4 + fkg) ^ sx) << 4));
    };
    auto ldB = [&](int buf, int j, int ks) -> bf16x8 {
        int row = wc*64 + j*16 + fr;                  // row&7 == sx
        return *(const bf16x8*)(smem + buf*32768 + 16384 + row*128 + (((ks*4 + fkg) ^ sx) << 4));
    };

    stage(0, 0);
    __syncthreads();

    for (int kt = 0; kt < NT; ++kt) {
        const int cur = kt & 1;
        if (kt + 1 < NT) stage(kt + 1, cur ^ 1);
        bf16x8 b[4][2], a[4][2];
        #pragma unroll
        for (int j = 0; j < 4; j++) { b[j][0] = ldB(cur, j, 0); b[j][1] = ldB(cur, j, 1); }
        #pragma unroll
        for (int i = 0; i < 4; i++) { a[i][0] = ldA(cur, i, 0); a[i][1] = ldA(cur, i, 1); }
        __builtin_amdgcn_s_setprio(1);
        #pragma unroll
        for (int i = 0; i < 4; i++)
            #pragma unroll
            for (int j = 0; j < 4; j++) {
                acc[i][j] = MFMA_BF16(a[i][0], b[j][0], acc[i][j]);
                acc[i][j] = MFMA_BF16(a[i][1], b[j][1], acc[i][j]);
            }
        __builtin_amdgcn_s_setprio(0);
        __syncthreads();
    }

    const int colL = lane & 15, rowg = (lane >> 4) * 4;
    #pragma unroll
    for (int i = 0; i < 4; i++) {
        #pragma unroll
        for (int j = 0; j < 4; j++) {
            int col = n0 + wc*64 + j*16 + colL;
            float bv = bias ? bias[col] : 0.0f;
            #pragma unroll
            for (int r = 0; r < 4; r++) {
                int row = m0 + wr*64 + i*16 + rowg + r;
                float v = acc[i][j][r] + bv;
                if (flags & 4) v = fmaxf(v, 0.0f);
                size_t off = (size_t)row * ldc + col;
                if (flags & 1)      ((__hip_bfloat16*)Cp)[off] = __float2bfloat16(v);
                else if (flags & 2) ((float*)Cp)[off] += v;
                else                ((float*)Cp)[off] = v;
            }
        }
    }
}

// ---------------- attention (vectorized bf16x8 loads) ----------------
__global__ __launch_bounds__(256) void k_attn(const __hip_bfloat16* __restrict__ qkv,
                                              __hip_bfloat16* __restrict__ o) {
    __shared__ float qs[SEQ_][HD_], ks[SEQ_][HD_], vs[SEQ_][HD_];
    __shared__ float att[SEQ_][SEQ_];
    int blk = blockIdx.x;
    int hh  = blk % H_;
    int cbb = blk / H_;
    int t = threadIdx.x;
    if (t < 96) {                          // 12 rows x 8 chunks of 8 elems
        int s = t >> 3, c = (t & 7) * 8;
        size_t base = (size_t)(cbb*SEQ_ + s) * 2304 + hh*64 + c;
        bf16x8 q8 = *(const bf16x8*)(qkv + base);
        bf16x8 k8 = *(const bf16x8*)(qkv + base + 768);
        bf16x8 v8 = *(const bf16x8*)(qkv + base + 1536);
        #pragma unroll
        for (int j = 0; j < 8; j++) {
            qs[s][c+j] = __uint_as_float((unsigned)(unsigned short)q8[j] << 16);
            ks[s][c+j] = __uint_as_float((unsigned)(unsigned short)k8[j] << 16);
            vs[s][c+j] = __uint_as_float((unsigned)(unsigned short)v8[j] << 16);
        }
    }
    __syncthreads();
    if (t < SEQ_*SEQ_) {
        int qi = t / SEQ_, kj = t % SEQ_;
        float s = 0.f;
        #pragma unroll
        for (int d = 0; d < HD_; d++) s += qs[qi][d] * ks[kj][d];
        att[qi][kj] = s * 0.125f;
    }
    __syncthreads();
    if (t < SEQ_) {
        float mx = -1e30f;
        #pragma unroll
        for (int j = 0; j < SEQ_; j++) mx = fmaxf(mx, att[t][j]);
        float e[SEQ_]; float sum = 0.f;
        #pragma unroll
        for (int j = 0; j < SEQ_; j++) { e[j] = expf(att[t][j] - mx); sum += e[j]; }
        float inv = 1.f / sum;
        #pragma unroll
        for (int j = 0; j < SEQ_; j++) att[t][j] = e[j] * inv;
    }
    __syncthreads();
    for (int i = t; i < SEQ_*HD_; i += 256) {
        int s = i / HD_, d = i % HD_;
        float acc = 0.f;
        #pragma unroll
        for (int j = 0; j < SEQ_; j++) acc += att[s][j] * vs[j][d];
        o[(size_t)(cbb*SEQ_ + s) * 768 + hh*64 + d] = __float2bfloat16(acc);
    }
}

// ---------------- logits ----------------
__global__ __launch_bounds__(256) void k_logits(const __hip_bfloat16* __restrict__ hfin,
                                                const float* __restrict__ Wout,
                                                const float* __restrict__ bout,
                                                float* __restrict__ logits, int cb) {
    __shared__ float red[3][256];
    int blk = blockIdx.x;
    int t = threadIdx.x;
    const __hip_bfloat16* row = hfin + (size_t)blk * SEQ_ * E_;
    float a0 = 0.f, a1 = 0.f, a2 = 0.f;
    for (int e = t; e < SEQ_*E_; e += 256) {
        float x = __bfloat162float(row[e]);
        a0 += x * Wout[e*3 + 0]; a1 += x * Wout[e*3 + 1]; a2 += x * Wout[e*3 + 2];
    }
    red[0][t] = a0; red[1][t] = a1; red[2][t] = a2;
    __syncthreads();
    for (int o = 128; o > 0; o >>= 1) {
        if (t < o) { red[0][t] += red[0][t+o]; red[1][t] += red[1][t+o]; red[2][t] += red[2][t+o]; }
        __syncthreads();
    }
    if (t < 3) logits[((size_t)cb*B_ + blk)*3 + t] = red[t][0] + bout[t];
}

// ---------------- greedy matching: ONE wave, lazy-rescan row-cache ----------------
// (round-4 version: measured 355 us; eager 2-min variant regressed to 501 us)
__global__ __launch_bounds__(64) void k_match(const float* __restrict__ logits,
                                              const float* __restrict__ targets,
                                              float* __restrict__ losses) {
    __shared__ float cst[128 * 129];       // pad 129: bank (r+c)%32, 2-way max
    __shared__ float tg[128][3];
    __shared__ int mrow[128];
    int cl = blockIdx.x, lane = threadIdx.x;
    int lidx = cl + 1;
    for (int j = lane; j < 128; j += 64) {
        const float* tp = &targets[((size_t)j*L_ + (L_ - lidx)) * 3];
        tg[j][0] = tp[0]; tg[j][1] = tp[1]; tg[j][2] = tp[2];
    }
    __syncthreads();
    u64 kc[2];
    #pragma unroll
    for (int hh = 0; hh < 2; hh++) {
        int r = lane + hh*64;
        const float* lg = &logits[(cl*B_ + r) * 3];
        float l0 = lg[0], l1 = lg[1], l2 = lg[2];
        u64 best = ~0ull;
        for (int c = 0; c < 128; c++) {
            float d0 = l0 - tg[c][0], d1 = l1 - tg[c][1], d2 = l2 - tg[c][2];
            float cc = sqrtf(d0*d0 + d1*d1 + d2*d2 + 1e-12f);
            cst[r*129 + c] = cc;
            u64 key = ((u64)__float_as_uint(cc) << 14) | (unsigned)(r*128 + c);
            best = key < best ? key : best;
        }
        kc[hh] = best;
    }
    __syncthreads();                       // all rows of cst visible to all lanes
    u64 dead0 = 0, dead1 = 0;
    int done = 0;
    for (int trip = 0; trip < 16640 && done < 128; trip++) {
        u64 b = kc[0] < kc[1] ? kc[0] : kc[1];
        #pragma unroll
        for (int o = 32; o > 0; o >>= 1) {
            u64 x = __shfl_xor(b, o, 64);
            b = x < b ? x : b;
        }
        unsigned e  = (unsigned)b & 0x3fffu;
        unsigned wi = e >> 7, wj = e & 127;
        bool isDead = (((wj < 64) ? (dead0 >> wj) : (dead1 >> (wj - 64))) & 1ull) != 0;
        if (!isDead) {                     // wave-uniform branch
            if ((wi & 63u) == (unsigned)lane) {
                mrow[wi] = (int)wj;
                kc[wi >> 6] = ~0ull;
            }
            if (wj < 64) dead0 |= 1ull << wj; else dead1 |= 1ull << (wj - 64);
            done++;
        } else {                           // stale winner: rescan row wi cooperatively
            float c0 = cst[wi*129 + lane];
            float c1 = cst[wi*129 + lane + 64];
            bool d0b = ((dead0 >> lane) & 1ull) != 0;
            bool d1b = ((dead1 >> lane) & 1ull) != 0;
            u64 k0 = d0b ? ~0ull : (((u64)__float_as_uint(c0) << 14) | (unsigned)(wi*128 + lane));
            u64 k1 = d1b ? ~0ull : (((u64)__float_as_uint(c1) << 14) | (unsigned)(wi*128 + lane + 64));
            u64 nb = k0 < k1 ? k0 : k1;
            #pragma unroll
            for (int o = 32; o > 0; o >>= 1) {
                u64 x = __shfl_xor(nb, o, 64);
                nb = x < nb ? x : nb;
            }
            if ((wi & 63u) == (unsigned)lane) kc[wi >> 6] = nb;
        }
    }
    __syncthreads();
    float a = 0.f;
    #pragma unroll
    for (int hh = 0; hh < 2; hh++) {
        int r = lane + hh*64;
        const float* lg = &logits[(cl*B_ + mrow[r]) * 3];
        float d0 = lg[0]-tg[r][0], d1 = lg[1]-tg[r][1], d2 = lg[2]-tg[r][2];
        a += d0*d0 + d1*d1 + d2*d2;
    }
    #pragma unroll
    for (int o = 32; o > 0; o >>= 1) a += __shfl_xor(a, o, 64);
    if (lane == 0) losses[cl] = a * (1.0f / (B_*3));
}

__global__ void k_final(const float* __restrict__ losses, float* __restrict__ out) {
    float s = 0.f;
    for (int i = 0; i < 15; i++) s += losses[i];
    out[0] = s * (1.0f / 15.0f);
}

extern "C" void kernel_launch(void* const* d_in, const int* in_sizes, int n_in,
                              void* d_out, int out_size, void* d_ws, size_t ws_size,
                              hipStream_t stream) {
    (void)in_sizes; (void)n_in; (void)out_size;
    const float* X       = (const float*)d_in[0];
    const float* targets = (const float*)d_in[1];
    const float* omegas  = (const float*)d_in[2];
    const float* phases  = (const float*)d_in[3];
    const int*   perms   = (const int*)d_in[4];
    const float* Wq  = (const float*)d_in[5];
    const float* bq  = (const float*)d_in[6];
    const float* Wk  = (const float*)d_in[7];
    const float* bk  = (const float*)d_in[8];
    const float* Wv  = (const float*)d_in[9];
    const float* bv  = (const float*)d_in[10];
    const float* Wo  = (const float*)d_in[11];
    const float* bo  = (const float*)d_in[12];
    const float* ln1g = (const float*)d_in[13];
    const float* ln1b = (const float*)d_in[14];
    const float* ln2g = (const float*)d_in[15];
    const float* ln2b = (const float*)d_in[16];
    const float* W1  = (const float*)d_in[17];
    const float* b1f = (const float*)d_in[18];
    const float* W2  = (const float*)d_in[19];
    const float* b2f = (const float*)d_in[20];
    const float* lnfg = (const float*)d_in[21];
    const float* lnfb = (const float*)d_in[22];
    const float* Wout = (const float*)d_in[23];
    const float* bout = (const float*)d_in[24];

    // ws_size constant across calls -> branches are call-invariant (graph-safe).
    int CL; bool hoist;
    if (ws_size >= 263000000ull)      { CL = 15; hoist = false; }
    else if (ws_size >= 169000000ull) { CL = 5;  hoist = true;  }
    else                              { CL = 5;  hoist = false; }
    int M = CL * B_ * SEQ_;
    bool perLayerCvt = (CL == 15) || !hoist;

    char* wsb = (char*)d_ws;
    size_t off = 0;
    auto alloc = [&](size_t bytes) {
        char* p = wsb + off;
        off += (bytes + 255) & ~(size_t)255;
        return p;
    };
    float*          x      = (float*)alloc((size_t)M*E_*4);
    __hip_bfloat16* h      = (__hip_bfloat16*)alloc((size_t)M*E_*2);
    __hip_bfloat16* qkvh   = (__hip_bfloat16*)alloc((size_t)M*3072*2);  // qkv(2304) | ffn hidden(3072)
    __hip_bfloat16* wl     = (__hip_bfloat16*)alloc((hoist ? 6 : 1) * (size_t)WLS*2);
    float*          bqkv   = (float*)alloc((hoist ? 6 : 1) * (size_t)BQS*4);
    float*          logits = (float*)alloc(23040);
    float*          losses = (float*)alloc(64);

    if (hoist)
        k_cvt<<<6*6913, 256, 0, stream>>>(Wq, Wk, Wv, Wo, W1, W2, bq, bk, bv, wl, bqkv, 0);

    dim3 gQKV(2304/128, M/128);
    dim3 gF1 (3072/128, M/128);
    dim3 gN  (768/128,  M/128);
    dim3 gLN (M/4);

    for (int cb = 0; cb < 15; cb += CL) {
        k_x0<<<(M*E_)/256, 256, 0, stream>>>(X, targets, perms, omegas, phases, x, cb, M);
        for (int l = 0; l < NL_; l++) {
            __hip_bfloat16* wlp = hoist ? wl + (size_t)l*WLS : wl;
            float*          bqp = hoist ? bqkv + l*BQS : bqkv;
            if (perLayerCvt)
                k_cvt<<<6913, 256, 0, stream>>>(Wq, Wk, Wv, Wo, W1, W2, bq, bk, bv, wlp, bqp, l);
            k_ln<<<gLN, 256, 0, stream>>>(x, ln1g + l*E_, ln1b + l*E_, h);
            k_gemm128<<<gQKV, 256, 0, stream>>>(h, wlp, bqp, qkvh, 768, 768, 2304, 1);
            k_attn<<<CL*B_*H_, 256, 0, stream>>>(qkvh, h);
            k_gemm128<<<gN, 256, 0, stream>>>(h, wlp + 1769472, bo + l*E_, x,
                                              768, 768, 768, 2);
            k_ln<<<gLN, 256, 0, stream>>>(x, ln2g + l*E_, ln2b + l*E_, h);
            k_gemm128<<<gF1, 256, 0, stream>>>(h, wlp + 2359296, b1f + l*3072, qkvh,
                                               768, 768, 3072, 1|4);
            k_gemm128<<<gN, 256, 0, stream>>>(qkvh, wlp + 4718592, b2f + l*E_, x,
                                              3072, 3072, 768, 2);
        }
        k_ln<<<gLN, 256, 0, stream>>>(x, lnfg, lnfb, h);
        k_logits<<<CL*B_, 256, 0, stream>>>(h, Wout, bout, logits, cb);
    }
    k_match<<<15, 64, 0, stream>>>(logits, targets, losses);
    k_final<<<1, 1, 0, stream>>>(losses, (float*)d_out);
}